// Round 6
// baseline (311.624 us; speedup 1.0000x reference)
//
#include <hip/hip_runtime.h>
#include <hip/hip_bf16.h>
#include <math.h>

#define N_NODES 51200
#define N_EDGES 614400
#define N_GRAPHS 256
#define T_CAPS 8
#define D_DIM 128
#define BN_EPS 1e-5f

__device__ inline float waveReduceSum(float v) {
#pragma unroll
  for (int off = 1; off < 64; off <<= 1) v += __shfl_xor(v, off, 64);
  return v;
}

__device__ inline float bf_lo(unsigned u) { return __uint_as_float(u << 16); }
__device__ inline float bf_hi(unsigned u) { return __uint_as_float(u & 0xffff0000u); }

// ---- prep: zero scratch + graph bounds from sorted batch + W transpose ----
__global__ void prep(const int* __restrict__ batch, const float* __restrict__ W,
                     int* __restrict__ start, int* __restrict__ cnt_in,
                     int* __restrict__ cursor, float* __restrict__ deg,
                     float* __restrict__ WT) {
  int i = blockIdx.x * 256 + threadIdx.x;  // 51200 threads
  cnt_in[i] = 0;
  cursor[i] = 0;
  deg[i] = 0.f;
  int bn = batch[i];
  if (i == 0) {
    for (int g = 0; g <= bn; g++) start[g] = 0;
  } else {
    int bp = batch[i - 1];
    for (int g = bp + 1; g <= bn; g++) start[g] = i;
  }
  if (i == N_NODES - 1) {
    for (int g = bn + 1; g <= N_GRAPHS; g++) start[g] = N_NODES;
  }
  for (int j = i; j < T_CAPS * D_DIM * D_DIM; j += N_NODES) {
    int t = j >> 14, r = j & 16383;
    int oo = r >> 7, o = r & 127;
    WT[j] = W[(t * D_DIM + o) * D_DIM + oo];
  }
}

// ---- per-graph x row-sums and row-sumsq (single pass over x) ----
__global__ void __launch_bounds__(512) xstats(const float* __restrict__ x,
                                              const int* __restrict__ start,
                                              float* __restrict__ rawxsum,
                                              float* __restrict__ rawxsq) {
  int g = blockIdx.x;
  int tid = threadIdx.x;
  int d = tid & 127, h = tid >> 7;
  int st = start[g], en = start[g + 1];
  float s = 0.f, s2 = 0.f;
  for (int n = st + h; n < en; n += 4) {
    float v = x[n * D_DIM + d];
    s += v;
    s2 += v * v;
  }
  __shared__ float ls[512], ls2[512];
  ls[tid] = s;
  ls2[tid] = s2;
  __syncthreads();
  if (h == 0) {
    rawxsum[g * D_DIM + d] = ls[d] + ls[d + 128] + ls[d + 256] + ls[d + 384];
    rawxsq[g * D_DIM + d] = ls2[d] + ls2[d + 128] + ls2[d + 256] + ls2[d + 384];
  }
}

// one block per feature d, 256 threads over graphs
__global__ void finalize_bn(const float* __restrict__ rawxsum, const float* __restrict__ rawxsq,
                            const float* __restrict__ gamma, const float* __restrict__ beta,
                            float* __restrict__ scale, float* __restrict__ shift) {
  int d = blockIdx.x;
  int g = threadIdx.x;
  __shared__ float ls[256], ls2[256];
  ls[g] = rawxsum[g * D_DIM + d];
  ls2[g] = rawxsq[g * D_DIM + d];
  __syncthreads();
  for (int off = 128; off; off >>= 1) {
    if (g < off) {
      ls[g] += ls[g + off];
      ls2[g] += ls2[g + off];
    }
    __syncthreads();
  }
  if (g == 0) {
    float mu = ls[0] * (1.0f / N_NODES);
    float var = ls2[0] * (1.0f / N_NODES) - mu * mu;
    float rstd = rsqrtf(var + BN_EPS);
    float sc = gamma[d] * rstd;
    scale[d] = sc;
    shift[d] = beta[d] - mu * sc;
  }
}

// per-edge: in-degree histogram + weighted degree (random cols -> low contention)
__global__ void edge_hist(const int* __restrict__ col, const float* __restrict__ ew,
                          int* __restrict__ cnt_in, float* __restrict__ deg) {
  int e = blockIdx.x * blockDim.x + threadIdx.x;
  if (e < N_EDGES) {
    int c = col[e];
    atomicAdd(&cnt_in[c], 1);
    atomicAdd(&deg[c], ew[e]);
  }
}

// ---- 2-stage parallel scan of cnt_in (51200 = 200 x 256) ----
__global__ void scan_part(const int* __restrict__ cnt_in, int* __restrict__ bsum) {
  __shared__ int ls[256];
  int i = blockIdx.x * 256 + threadIdx.x;
  ls[threadIdx.x] = cnt_in[i];
  __syncthreads();
  for (int off = 128; off; off >>= 1) {
    if (threadIdx.x < off) ls[threadIdx.x] += ls[threadIdx.x + off];
    __syncthreads();
  }
  if (threadIdx.x == 0) bsum[blockIdx.x] = ls[0];
}

// each block reduces its prefix of bsum, then scans its 256 entries
__global__ void scan_fin2(const int* __restrict__ cnt_in, const int* __restrict__ bsum,
                          int* __restrict__ node_start) {
  __shared__ int ls[256];
  int t = threadIdx.x, bid = blockIdx.x;
  ls[t] = (t < bid) ? bsum[t] : 0;
  __syncthreads();
  for (int off = 128; off; off >>= 1) {
    if (t < off) ls[t] += ls[t + off];
    __syncthreads();
  }
  int base = ls[0];
  __syncthreads();
  int idx = bid * 256 + t;
  int v = cnt_in[idx];
  ls[t] = v;
  __syncthreads();
  for (int off = 1; off < 256; off <<= 1) {
    int u = (t >= off) ? ls[t - off] : 0;
    __syncthreads();
    ls[t] += u;
    __syncthreads();
  }
  node_start[idx] = base + ls[t] - v;
}

// bucket edges by destination: csr[slot] = (src, raw ew)
__global__ void fill_csr(const int* __restrict__ row, const int* __restrict__ col,
                         const float* __restrict__ ew, const int* __restrict__ node_start,
                         int* __restrict__ cursor, int2* __restrict__ csr) {
  int e = blockIdx.x * blockDim.x + threadIdx.x;
  if (e < N_EDGES) {
    int c = col[e];
    int slot = node_start[c] + atomicAdd(&cursor[c], 1);
    csr[slot] = make_int2(row[e], __float_as_int(ew[e]));
  }
}

// elementwise: dis = rsqrt(deg+1); y = bf16(dis * xhat)
__global__ void make_y(const float* __restrict__ x, const float* __restrict__ scale,
                       const float* __restrict__ shift, const float* __restrict__ deg,
                       float* __restrict__ dis, __hip_bfloat162* __restrict__ y) {
  int idx = blockIdx.x * 256 + threadIdx.x;
  int n = idx >> 6, l = idx & 63;
  float dv = deg[n] + 1.0f;  // + self-loop weight
  float dn = dv > 0.f ? rsqrtf(fmaxf(dv, 1e-12f)) : 0.f;
  if (l == 0) dis[n] = dn;
  float2 scv = ((const float2*)scale)[l];
  float2 shv = ((const float2*)shift)[l];
  float2 xv = ((const float2*)x)[n * 64 + l];
  float2 yv;
  yv.x = dn * (xv.x * scv.x + shv.x);
  yv.y = dn * (xv.y * scv.y + shv.y);
  y[n * 64 + l] = __float22bfloat162_rn(yv);
}

// one wave per node: agg[n] = bf16( dis[n] * (y[n] + sum_e ew_e * y[src_e]) )
__global__ void node_gather(const __hip_bfloat162* __restrict__ y, const float* __restrict__ dis,
                            const int* __restrict__ node_start, const int* __restrict__ cnt_in,
                            const int2* __restrict__ csr, __hip_bfloat162* __restrict__ agg) {
  int n = blockIdx.x * 4 + (threadIdx.x >> 6);
  int lane = threadIdx.x & 63;
  int st = node_start[n], c = cnt_in[n];
  float2 a = __bfloat1622float2(y[n * 64 + lane]);  // self term
  int j = 0;
  for (; j + 4 <= c; j += 4) {
    int2 e0 = csr[st + j], e1 = csr[st + j + 1], e2 = csr[st + j + 2], e3 = csr[st + j + 3];
    float2 v0 = __bfloat1622float2(y[e0.x * 64 + lane]);
    float2 v1 = __bfloat1622float2(y[e1.x * 64 + lane]);
    float2 v2 = __bfloat1622float2(y[e2.x * 64 + lane]);
    float2 v3 = __bfloat1622float2(y[e3.x * 64 + lane]);
    float w0 = __int_as_float(e0.y), w1 = __int_as_float(e1.y);
    float w2 = __int_as_float(e2.y), w3 = __int_as_float(e3.y);
    a.x += w0 * v0.x + w1 * v1.x + w2 * v2.x + w3 * v3.x;
    a.y += w0 * v0.y + w1 * v1.y + w2 * v2.y + w3 * v3.y;
  }
  for (; j < c; j++) {
    int2 e = csr[st + j];
    float2 v = __bfloat1622float2(y[e.x * 64 + lane]);
    float w = __int_as_float(e.y);
    a.x += w * v.x;
    a.y += w * v.y;
  }
  float dn = dis[n];
  a.x *= dn;
  a.y *= dn;
  agg[n * 64 + lane] = __float22bfloat162_rn(a);
}

// ---- whole routing phase: one block (1024 thr) per graph, bf16 agg, dbuf tiles ----
__global__ void __launch_bounds__(1024) routing_fused(
    const unsigned* __restrict__ agg_bf, const int* __restrict__ start,
    const float* __restrict__ W, const float* __restrict__ WT, const float* __restrict__ bias,
    const float* __restrict__ rawxsum, const float* __restrict__ scale,
    const float* __restrict__ shift, float* __restrict__ b, float* __restrict__ out) {
  int g = blockIdx.x;
  int tid = threadIdx.x;
  int st = start[g], c = start[g + 1] - st;

  __shared__ unsigned short atile[2][64][136];  // bf16 tiles (pad 8 -> row stride 272B)
  __shared__ float ac_sh[T_CAPS][132];
  __shared__ float s_sh[T_CAPS][132];
  __shared__ float wv_sh[T_CAPS][132];
  __shared__ float dtsh[64][9];
  __shared__ float csh[64][9];
  __shared__ float csum_sh[T_CAPS], bv_sh[T_CAPS], f_sh[T_CAPS], s2p[T_CAPS][2];

  float* scratch = (float*)&atile[0][0][0];  // aliased; used only when tiles dead
  const uint4* aggb4 = (const uint4*)agg_bf;  // 16 uint4 per 256B row

  // Phase 0: aggsum/8 -> ac_sh (uniform c=1/8); csum = c/8
  {
    int d2 = tid & 63, h = tid >> 6;  // 16-way over nodes
    float sx = 0.f, sy = 0.f;
    for (int n = st + h; n < st + c; n += 16) {
      unsigned u = agg_bf[n * 64 + d2];
      sx += bf_lo(u);
      sy += bf_hi(u);
    }
    scratch[h * 128 + d2 * 2] = sx;
    scratch[h * 128 + d2 * 2 + 1] = sy;
  }
  __syncthreads();
  if (tid < 128) {
    float s = 0.f;
#pragma unroll
    for (int h = 0; h < 16; h++) s += scratch[h * 128 + tid];
    s *= 0.125f;
#pragma unroll
    for (int t = 0; t < T_CAPS; t++) ac_sh[t][tid] = s;
  }
  if (tid < T_CAPS) csum_sh[tid] = 0.125f * (float)c;
  __syncthreads();

  int tG = tid >> 7, oG = tid & 127;                    // GEMV: one thread per (t,o)
  int nLp = tid >> 4, tLp = (tid >> 1) & 7, half = tid & 1;  // proj layout
  int tA = tid >> 7, rep = (tid >> 5) & 3, d4A = (tid & 31) << 2;  // accum layout
  int rS = tid >> 4, sS = tid & 15;                     // staging: row, 16B segment
  int ntiles = (c + 63) >> 6;

  for (int iter = 0; iter < 3; iter++) {
    // GEMV1: s[t][o] = ac_sh[t]·W[t][:,o] + csum*bias (+ x_mean on last iter)
    {
      const float* Wt = W + tG * D_DIM * D_DIM;
      float s = 0.f;
#pragma unroll 8
      for (int dd = 0; dd < D_DIM; dd++) s += ac_sh[tG][dd] * Wt[dd * D_DIM + oG];
      s += csum_sh[tG] * bias[tG * D_DIM + oG];
      if (iter == 2) {
        float cf = (float)c;
        float ic = 1.0f / fmaxf(cf, 1.0f);
        s += (scale[oG] * rawxsum[g * D_DIM + oG] + cf * shift[oG]) * ic;
      }
      s_sh[tG][oG] = s;
      float p = waveReduceSum(s * s);
      if ((tid & 63) == 0) s2p[tG][(tid >> 6) & 1] = p;
    }
    __syncthreads();
    if (tid < T_CAPS) {
      float s2 = s2p[tid][0] + s2p[tid][1];
      float f = (s2 / (1.0f + s2)) * rsqrtf(s2 + 1e-16f);
      f_sh[tid] = f;
      if (iter == 2) out[g * T_CAPS + tid] = sqrtf(f * f * s2 + 1e-16f);
    }
    __syncthreads();
    if (iter == 2) return;
    s_sh[tG][oG] *= f_sh[tG];  // s -> v in place
    __syncthreads();
    // GEMV2: wv[t][o] = WT[t][:,o]·v ; bv[t] = bias[t]·v
    {
      const float* WTt = WT + tG * D_DIM * D_DIM;
      float s = 0.f;
#pragma unroll 8
      for (int oo = 0; oo < D_DIM; oo++) s += s_sh[tG][oo] * WTt[oo * D_DIM + oG];
      wv_sh[tG][oG] = s;
      float bp = bias[tG * D_DIM + oG] * s_sh[tG][oG];
      bp = waveReduceSum(bp);
      if ((tid & 63) == 0) s2p[tG][(tid >> 6) & 1] = bp;
    }
    __syncthreads();
    if (tid < T_CAPS) bv_sh[tid] = s2p[tid][0] + s2p[tid][1];
    __syncthreads();

    // ---- node pass over this graph's rows (double-buffered bf16 tiles) ----
    float4 acc = make_float4(0.f, 0.f, 0.f, 0.f);
    float csl = 0.f;
    if (ntiles > 0) {  // stage tile 0
      int nv0 = min(64, c);
      uint4 v = make_uint4(0, 0, 0, 0);
      if (rS < nv0) v = aggb4[(size_t)(st + rS) * 16 + sS];
      *(uint4*)&atile[0][rS][sS * 8] = v;
    }
    __syncthreads();
    int buf = 0;
    for (int tile = 0; tile < ntiles; tile++) {
      int n0 = tile << 6;
      int nv = min(64, c - n0);
      // prefetch next tile into registers (lands during compute)
      uint4 pre = make_uint4(0, 0, 0, 0);
      if (tile + 1 < ntiles) {
        int nvn = min(64, c - ((tile + 1) << 6));
        if (rS < nvn) pre = aggb4[(size_t)(st + ((tile + 1) << 6) + rS) * 16 + sS];
      }
      // proj: (nL, tL, half): half-dot over 64 elems
      float pr = 0.f;
      const unsigned short* rowp = &atile[buf][nLp][0];
#pragma unroll 8
      for (int k = 0; k < 16; k++) {
        uint2 u = *(const uint2*)(rowp + half * 64 + k * 4);
        float4 wq = *(const float4*)&wv_sh[tLp][half * 64 + k * 4];
        pr += bf_lo(u.x) * wq.x + bf_hi(u.x) * wq.y + bf_lo(u.y) * wq.z + bf_hi(u.y) * wq.w;
      }
      pr += __shfl_xor(pr, 1, 64);
      float dt = 0.f;
      if (half == 0) {
        dt = pr + bv_sh[tLp];
        int gn = st + n0 + nLp;
        if (nLp < nv) {
          if (iter == 1) dt += b[gn * T_CAPS + tLp];
          b[gn * T_CAPS + tLp] = dt;
        }
        dtsh[nLp][tLp] = dt;
      }
      __syncthreads();
      if (half == 0) {
        float cval = 0.f;
        if (nLp < nv) {
          float m = dtsh[nLp][0];
#pragma unroll
          for (int q = 1; q < T_CAPS; q++) m = fmaxf(m, dtsh[nLp][q]);
          float Z = 0.f;
#pragma unroll
          for (int q = 0; q < T_CAPS; q++) Z += __expf(dtsh[nLp][q] - m);
          cval = __expf(dt - m) / Z;
          csl += cval;
        }
        csh[nLp][tLp] = cval;
      }
      __syncthreads();
      // accumulate: (t, rep, d4) over tile nodes
      for (int nj = rep; nj < nv; nj += 4) {
        float cj = csh[nj][tA];
        uint2 u = *(const uint2*)(&atile[buf][nj][0] + d4A);
        acc.x += cj * bf_lo(u.x);
        acc.y += cj * bf_hi(u.x);
        acc.z += cj * bf_lo(u.y);
        acc.w += cj * bf_hi(u.y);
      }
      __syncthreads();
      if (tile + 1 < ntiles) *(uint4*)&atile[buf ^ 1][rS][sS * 8] = pre;
      __syncthreads();
      buf ^= 1;
    }
    // merge accumulators (scratch aliases tiles — dead now)
    if (half == 0) dtsh[nLp][tLp] = csl;
    if (rep > 0) *(float4*)&scratch[(((rep - 1) << 3) + tA) * 128 + d4A] = acc;
    __syncthreads();
    if (rep == 0) {
#pragma unroll
      for (int m = 0; m < 3; m++) {
        float4 o4 = *(const float4*)&scratch[((m << 3) + tA) * 128 + d4A];
        acc.x += o4.x;
        acc.y += o4.y;
        acc.z += o4.z;
        acc.w += o4.w;
      }
      *(float4*)&ac_sh[tA][d4A] = acc;
    }
    if (tid < T_CAPS) {
      float s = 0.f;
#pragma unroll
      for (int q = 0; q < 64; q++) s += dtsh[q][tid];
      csum_sh[tid] = s;
    }
    __syncthreads();
  }
}

extern "C" void kernel_launch(void* const* d_in, const int* in_sizes, int n_in, void* d_out,
                              int out_size, void* d_ws, size_t ws_size, hipStream_t stream) {
  const float* x = (const float*)d_in[0];
  const float* ew = (const float*)d_in[1];
  const float* gamma = (const float*)d_in[2];
  const float* beta = (const float*)d_in[3];
  const float* W = (const float*)d_in[4];
  const float* bias = (const float*)d_in[5];
  const int* eidx = (const int*)d_in[6];
  const int* batch = (const int*)d_in[7];
  float* out = (float*)d_out;
  float* w = (float*)d_ws;

  const int* row = eidx;
  const int* col = eidx + N_EDGES;

  int* cnt_in = (int*)w;                       // N (zeroed in prep)
  int* cursor = cnt_in + N_NODES;              // N (zeroed in prep)
  float* deg = (float*)(cursor + N_NODES);     // N (zeroed in prep)
  int* start = (int*)(deg + N_NODES);          // 258 (even pad)
  int* node_start = start + 258;               // N
  int* bsum = node_start + N_NODES;            // 256
  float* scale = (float*)(bsum + 256);         // 128
  float* shift = scale + 128;                  // 128
  float* dis = shift + 128;                    // N
  float* rawxsum = dis + N_NODES;              // 256*128
  float* rawxsq = rawxsum + N_GRAPHS * D_DIM;  // 256*128
  float* WT = rawxsq + N_GRAPHS * D_DIM;       // 131072
  int2* csr = (int2*)(WT + T_CAPS * D_DIM * D_DIM);        // E
  __hip_bfloat162* y = (__hip_bfloat162*)(csr + N_EDGES);  // N*64
  unsigned* agg_bf = (unsigned*)(y + (size_t)N_NODES * 64);  // N*64 (packed bf16x2)
  float* b = (float*)(agg_bf + (size_t)N_NODES * 64);        // N*8

  prep<<<N_NODES / 256, 256, 0, stream>>>(batch, W, start, cnt_in, cursor, deg, WT);
  edge_hist<<<N_EDGES / 256, 256, 0, stream>>>(col, ew, cnt_in, deg);
  scan_part<<<200, 256, 0, stream>>>(cnt_in, bsum);
  scan_fin2<<<200, 256, 0, stream>>>(cnt_in, bsum, node_start);
  fill_csr<<<N_EDGES / 256, 256, 0, stream>>>(row, col, ew, node_start, cursor, csr);
  xstats<<<N_GRAPHS, 512, 0, stream>>>(x, start, rawxsum, rawxsq);
  finalize_bn<<<D_DIM, 256, 0, stream>>>(rawxsum, rawxsq, gamma, beta, scale, shift);
  make_y<<<(N_NODES * 64) / 256, 256, 0, stream>>>(x, scale, shift, deg, dis, y);
  node_gather<<<N_NODES / 4, 256, 0, stream>>>(y, dis, node_start, cnt_in, csr,
                                               (__hip_bfloat162*)agg_bf);
  routing_fused<<<N_GRAPHS, 1024, 0, stream>>>(agg_bf, start, W, WT, bias, rawxsum, scale,
                                               shift, b, out);
}

// Round 7
// 277.098 us; speedup vs baseline: 1.1246x; 1.1246x over previous
//
#include <hip/hip_runtime.h>
#include <hip/hip_bf16.h>
#include <math.h>

#define N_NODES 51200
#define N_EDGES 614400
#define N_GRAPHS 256
#define T_CAPS 8
#define D_DIM 128
#define BN_EPS 1e-5f
#define MAXC 512  // max nodes per graph handled per chunk (mean 200, sd ~14)

__device__ inline float waveReduceSum(float v) {
#pragma unroll
  for (int off = 1; off < 64; off <<= 1) v += __shfl_xor(v, off, 64);
  return v;
}

__device__ inline float bf_lo(unsigned u) { return __uint_as_float(u << 16); }
__device__ inline float bf_hi(unsigned u) { return __uint_as_float(u & 0xffff0000u); }

// ---- prep: zero scratch + graph bounds + W transpose (coalesced reads) ----
__global__ void prep(const int* __restrict__ batch, const float* __restrict__ W,
                     int* __restrict__ start, int* __restrict__ cnt_in,
                     int* __restrict__ cursor, float* __restrict__ WT) {
  int i = blockIdx.x * 256 + threadIdx.x;  // 51200 threads
  cnt_in[i] = 0;
  cursor[i] = 0;
  int bn = batch[i];
  if (i == 0) {
    for (int g = 0; g <= bn; g++) start[g] = 0;
  } else {
    int bp = batch[i - 1];
    for (int g = bp + 1; g <= bn; g++) start[g] = i;
  }
  if (i == N_NODES - 1) {
    for (int g = bn + 1; g <= N_GRAPHS; g++) start[g] = N_NODES;
  }
  // read W linearly (coalesced), scatter into WT; 512KB -> L2 absorbs writes
  for (int j = i; j < T_CAPS * D_DIM * D_DIM; j += N_NODES) {
    int t = j >> 14, r = j & 16383;
    int o = r >> 7, oo = r & 127;
    WT[(t << 14) + (oo << 7) + o] = W[j];
  }
}

// ---- per-graph x row-sums and row-sumsq (single pass over x) ----
__global__ void __launch_bounds__(512) xstats(const float* __restrict__ x,
                                              const int* __restrict__ start,
                                              float* __restrict__ rawxsum,
                                              float* __restrict__ rawxsq) {
  int g = blockIdx.x;
  int tid = threadIdx.x;
  int d = tid & 127, h = tid >> 7;
  int st = start[g], en = start[g + 1];
  float s = 0.f, s2 = 0.f;
  for (int n = st + h; n < en; n += 4) {
    float v = x[n * D_DIM + d];
    s += v;
    s2 += v * v;
  }
  __shared__ float ls[512], ls2[512];
  ls[tid] = s;
  ls2[tid] = s2;
  __syncthreads();
  if (h == 0) {
    rawxsum[g * D_DIM + d] = ls[d] + ls[d + 128] + ls[d + 256] + ls[d + 384];
    rawxsq[g * D_DIM + d] = ls2[d] + ls2[d + 128] + ls2[d + 256] + ls2[d + 384];
  }
}

__global__ void finalize_bn(const float* __restrict__ rawxsum, const float* __restrict__ rawxsq,
                            const float* __restrict__ gamma, const float* __restrict__ beta,
                            float* __restrict__ scale, float* __restrict__ shift) {
  int d = blockIdx.x;
  int g = threadIdx.x;
  __shared__ float ls[256], ls2[256];
  ls[g] = rawxsum[g * D_DIM + d];
  ls2[g] = rawxsq[g * D_DIM + d];
  __syncthreads();
  for (int off = 128; off; off >>= 1) {
    if (g < off) {
      ls[g] += ls[g + off];
      ls2[g] += ls2[g + off];
    }
    __syncthreads();
  }
  if (g == 0) {
    float mu = ls[0] * (1.0f / N_NODES);
    float var = ls2[0] * (1.0f / N_NODES) - mu * mu;
    float rstd = rsqrtf(var + BN_EPS);
    float sc = gamma[d] * rstd;
    scale[d] = sc;
    shift[d] = beta[d] - mu * sc;
  }
}

// per-edge in-degree histogram (single int atomic, random cols -> low contention)
__global__ void edge_hist(const int* __restrict__ col, int* __restrict__ cnt_in) {
  int e = blockIdx.x * blockDim.x + threadIdx.x;
  if (e < N_EDGES) atomicAdd(&cnt_in[col[e]], 1);
}

// ---- 2-stage parallel scan of cnt_in (51200 = 200 x 256) ----
__global__ void scan_part(const int* __restrict__ cnt_in, int* __restrict__ bsum) {
  __shared__ int ls[256];
  int i = blockIdx.x * 256 + threadIdx.x;
  ls[threadIdx.x] = cnt_in[i];
  __syncthreads();
  for (int off = 128; off; off >>= 1) {
    if (threadIdx.x < off) ls[threadIdx.x] += ls[threadIdx.x + off];
    __syncthreads();
  }
  if (threadIdx.x == 0) bsum[blockIdx.x] = ls[0];
}

__global__ void scan_fin2(const int* __restrict__ cnt_in, const int* __restrict__ bsum,
                          int* __restrict__ node_start) {
  __shared__ int ls[256];
  int t = threadIdx.x, bid = blockIdx.x;
  ls[t] = (t < bid) ? bsum[t] : 0;
  __syncthreads();
  for (int off = 128; off; off >>= 1) {
    if (t < off) ls[t] += ls[t + off];
    __syncthreads();
  }
  int base = ls[0];
  __syncthreads();
  int idx = bid * 256 + t;
  int v = cnt_in[idx];
  ls[t] = v;
  __syncthreads();
  for (int off = 1; off < 256; off <<= 1) {
    int u = (t >= off) ? ls[t - off] : 0;
    __syncthreads();
    ls[t] += u;
    __syncthreads();
  }
  node_start[idx] = base + ls[t] - v;
}

// bucket edges by destination: csr[slot] = (src, raw ew)
__global__ void fill_csr(const int* __restrict__ row, const int* __restrict__ col,
                         const float* __restrict__ ew, const int* __restrict__ node_start,
                         int* __restrict__ cursor, int2* __restrict__ csr) {
  int e = blockIdx.x * blockDim.x + threadIdx.x;
  if (e < N_EDGES) {
    int c = col[e];
    int slot = node_start[c] + atomicAdd(&cursor[c], 1);
    csr[slot] = make_int2(row[e], __float_as_int(ew[e]));
  }
}

// one wave per node: deg = sum(csr ew), dis = rsqrt(deg+1), y = bf16(dis*xhat)
__global__ void make_y(const float* __restrict__ x, const float* __restrict__ scale,
                       const float* __restrict__ shift, const int* __restrict__ node_start,
                       const int* __restrict__ cnt_in, const int2* __restrict__ csr,
                       float* __restrict__ dis, __hip_bfloat162* __restrict__ y) {
  int n = blockIdx.x * 4 + (threadIdx.x >> 6);
  int lane = threadIdx.x & 63;
  int st = node_start[n], c = cnt_in[n];
  float s = 0.f;
  for (int k = lane; k < c; k += 64) s += __int_as_float(csr[st + k].y);
  s = waveReduceSum(s);
  float dv = s + 1.0f;  // + self-loop weight
  float dn = dv > 0.f ? rsqrtf(fmaxf(dv, 1e-12f)) : 0.f;
  if (lane == 0) dis[n] = dn;
  float2 scv = ((const float2*)scale)[lane];
  float2 shv = ((const float2*)shift)[lane];
  float2 xv = ((const float2*)x)[n * 64 + lane];
  float2 yv;
  yv.x = dn * (xv.x * scv.x + shv.x);
  yv.y = dn * (xv.y * scv.y + shv.y);
  y[n * 64 + lane] = __float22bfloat162_rn(yv);
}

// one wave per node: agg[n] = bf16( dis[n] * (y[n] + sum_e ew_e * y[src_e]) )
__global__ void node_gather(const __hip_bfloat162* __restrict__ y, const float* __restrict__ dis,
                            const int* __restrict__ node_start, const int* __restrict__ cnt_in,
                            const int2* __restrict__ csr, __hip_bfloat162* __restrict__ agg) {
  int n = blockIdx.x * 4 + (threadIdx.x >> 6);
  int lane = threadIdx.x & 63;
  int st = node_start[n], c = cnt_in[n];
  float2 a = __bfloat1622float2(y[n * 64 + lane]);  // self term
  int j = 0;
  for (; j + 4 <= c; j += 4) {
    int2 e0 = csr[st + j], e1 = csr[st + j + 1], e2 = csr[st + j + 2], e3 = csr[st + j + 3];
    float2 v0 = __bfloat1622float2(y[e0.x * 64 + lane]);
    float2 v1 = __bfloat1622float2(y[e1.x * 64 + lane]);
    float2 v2 = __bfloat1622float2(y[e2.x * 64 + lane]);
    float2 v3 = __bfloat1622float2(y[e3.x * 64 + lane]);
    float w0 = __int_as_float(e0.y), w1 = __int_as_float(e1.y);
    float w2 = __int_as_float(e2.y), w3 = __int_as_float(e3.y);
    a.x += w0 * v0.x + w1 * v1.x + w2 * v2.x + w3 * v3.x;
    a.y += w0 * v0.y + w1 * v1.y + w2 * v2.y + w3 * v3.y;
  }
  for (; j < c; j++) {
    int2 e = csr[st + j];
    float2 v = __bfloat1622float2(y[e.x * 64 + lane]);
    float w = __int_as_float(e.y);
    a.x += w * v.x;
    a.y += w * v.y;
  }
  float dn = dis[n];
  a.x *= dn;
  a.y *= dn;
  agg[n * 64 + lane] = __float22bfloat162_rn(a);
}

// ---- routing v3: no agg LDS tiles, telescoped wv/bv (no b array), few syncs ----
__global__ void __launch_bounds__(1024) routing_fused(
    const unsigned* __restrict__ agg_bf, const int* __restrict__ start,
    const float* __restrict__ W, const float* __restrict__ WT, const float* __restrict__ bias,
    const float* __restrict__ rawxsum, const float* __restrict__ scale,
    const float* __restrict__ shift, float* __restrict__ out) {
  int g = blockIdx.x;
  int tid = threadIdx.x;
  int st = start[g], c = start[g + 1] - st;

  __shared__ float dt_sh[MAXC][T_CAPS];  // logits -> softmax coefs (in place); 16KB
  __shared__ float ac_sh[T_CAPS][D_DIM];
  __shared__ float s_sh[T_CAPS][D_DIM];
  __shared__ float wv_sh[T_CAPS][132];  // running wv (pad 132: proj 8-t reads)
  __shared__ float csum_sh[T_CAPS], bv_sh[T_CAPS], f_sh[T_CAPS], s2p[T_CAPS][2];
  __shared__ float csp_sh[32];

  float* scratch = &dt_sh[0][0];  // aliased scratch (4096 floats), used when dt dead
  const uint2* aggb2 = (const uint2*)agg_bf;
  const uint4* aggb4 = (const uint4*)agg_bf;

  // init running wv/bv; phase 0: ac = aggsum/8, csum = c/8
  for (int i = tid; i < T_CAPS * 132; i += 1024) (&wv_sh[0][0])[i] = 0.f;
  if (tid < T_CAPS) {
    bv_sh[tid] = 0.f;
    csum_sh[tid] = 0.125f * (float)c;
  }
  {
    int d2 = tid & 63, h = tid >> 6;  // 16-way over nodes
    float sx = 0.f, sy = 0.f;
    for (int n = st + h; n < st + c; n += 16) {
      unsigned u = agg_bf[n * 64 + d2];
      sx += bf_lo(u);
      sy += bf_hi(u);
    }
    scratch[h * 128 + d2 * 2] = sx;
    scratch[h * 128 + d2 * 2 + 1] = sy;
  }
  __syncthreads();
  if (tid < 128) {
    float s = 0.f;
#pragma unroll
    for (int h = 0; h < 16; h++) s += scratch[h * 128 + tid];
    s *= 0.125f;
#pragma unroll
    for (int t = 0; t < T_CAPS; t++) ac_sh[t][tid] = s;
  }
  __syncthreads();

  int tG = tid >> 7, oG = tid & 127;  // GEMV: one thread per (t,o)
  int nL = tid >> 3, tL = tid & 7;    // proj layout
  int tA = tid >> 7, rep = (tid >> 5) & 3, l32 = tid & 31;  // accum layout

  for (int iter = 0; iter < 3; iter++) {
    // GEMV1: s[t][o] = ac_sh[t]·W[t][:,o] + csum*bias (+ x_mean on last iter)
    {
      const float* Wt = W + (tG << 14);
      float s = 0.f;
#pragma unroll 8
      for (int dd = 0; dd < D_DIM; dd++) s += ac_sh[tG][dd] * Wt[dd * D_DIM + oG];
      s += csum_sh[tG] * bias[tG * D_DIM + oG];
      if (iter == 2) {
        float cf = (float)c;
        float ic = 1.0f / fmaxf(cf, 1.0f);
        s += (scale[oG] * rawxsum[g * D_DIM + oG] + cf * shift[oG]) * ic;
      }
      s_sh[tG][oG] = s;
      float p = waveReduceSum(s * s);
      if ((tid & 63) == 0) s2p[tG][(tid >> 6) & 1] = p;
    }
    __syncthreads();
    if (tid < T_CAPS) {
      float s2 = s2p[tid][0] + s2p[tid][1];
      float f = (s2 / (1.0f + s2)) * rsqrtf(s2 + 1e-16f);
      f_sh[tid] = f;
      if (iter == 2) out[g * T_CAPS + tid] = sqrtf(f * f * s2 + 1e-16f);
    }
    __syncthreads();
    if (iter == 2) return;
    s_sh[tG][oG] *= f_sh[tG];  // s -> v in place
    __syncthreads();
    // GEMV2: wv_run[t][o] += WT[t][:,o]·v ; bv_run[t] += bias[t]·v
    {
      const float* WTt = WT + (tG << 14);
      float s = 0.f;
#pragma unroll 8
      for (int oo = 0; oo < D_DIM; oo++) s += s_sh[tG][oo] * WTt[oo * D_DIM + oG];
      wv_sh[tG][oG] += s;
      float bp = bias[tG * D_DIM + oG] * s_sh[tG][oG];
      bp = waveReduceSum(bp);
      if ((tid & 63) == 0) s2p[tG][(tid >> 6) & 1] = bp;
    }
    __syncthreads();
    if (tid < T_CAPS) bv_sh[tid] += s2p[tid][0] + s2p[tid][1];
    __syncthreads();

    // ---- node sweep: logits -> softmax -> weighted accumulation (chunks of MAXC) ----
    float4 acc = make_float4(0.f, 0.f, 0.f, 0.f);
    float cslr = 0.f;
    for (int cb = 0; cb < c; cb += MAXC) {
      int nv = min(MAXC, c - cb);
      // proj: thread (nL, tL) full 128-dot from global (L2-hot)
      for (int n = nL; n < nv; n += 128) {
        const uint4* rowp = aggb4 + (size_t)(st + cb + n) * 16;
        float pr = 0.f;
#pragma unroll 4
        for (int k = 0; k < 16; k++) {
          uint4 u = rowp[k];
          float4 wa = *(const float4*)&wv_sh[tL][k * 8];
          float4 wb = *(const float4*)&wv_sh[tL][k * 8 + 4];
          pr += bf_lo(u.x) * wa.x + bf_hi(u.x) * wa.y + bf_lo(u.y) * wa.z + bf_hi(u.y) * wa.w;
          pr += bf_lo(u.z) * wb.x + bf_hi(u.z) * wb.y + bf_lo(u.w) * wb.z + bf_hi(u.w) * wb.w;
        }
        dt_sh[n][tL] = pr + bv_sh[tL];
      }
      __syncthreads();
      // softmax over t, in place
      if (tid < nv) {
        float l0 = dt_sh[tid][0], l1 = dt_sh[tid][1], l2 = dt_sh[tid][2], l3 = dt_sh[tid][3];
        float l4 = dt_sh[tid][4], l5 = dt_sh[tid][5], l6 = dt_sh[tid][6], l7 = dt_sh[tid][7];
        float m = fmaxf(fmaxf(fmaxf(l0, l1), fmaxf(l2, l3)),
                        fmaxf(fmaxf(l4, l5), fmaxf(l6, l7)));
        float e0 = __expf(l0 - m), e1 = __expf(l1 - m), e2 = __expf(l2 - m),
              e3 = __expf(l3 - m), e4 = __expf(l4 - m), e5 = __expf(l5 - m),
              e6 = __expf(l6 - m), e7 = __expf(l7 - m);
        float iz = 1.0f / (e0 + e1 + e2 + e3 + e4 + e5 + e6 + e7);
        dt_sh[tid][0] = e0 * iz;
        dt_sh[tid][1] = e1 * iz;
        dt_sh[tid][2] = e2 * iz;
        dt_sh[tid][3] = e3 * iz;
        dt_sh[tid][4] = e4 * iz;
        dt_sh[tid][5] = e5 * iz;
        dt_sh[tid][6] = e6 * iz;
        dt_sh[tid][7] = e7 * iz;
      }
      __syncthreads();
      // accumulate: thread (tA, rep, l32) over chunk nodes; coalesced 256B row reads
      for (int nj = rep; nj < nv; nj += 4) {
        float cj = dt_sh[nj][tA];
        uint2 u = aggb2[(size_t)(st + cb + nj) * 32 + l32];
        acc.x += cj * bf_lo(u.x);
        acc.y += cj * bf_hi(u.x);
        acc.z += cj * bf_lo(u.y);
        acc.w += cj * bf_hi(u.y);
        if (l32 == 0) cslr += cj;
      }
      __syncthreads();  // dt_sh reusable next chunk
    }
    // merge rep-partials via scratch (dt_sh dead now)
    int d4 = l32 << 2;
    if (rep > 0) *(float4*)&scratch[(((rep - 1) << 3) + tA) * 128 + d4] = acc;
    if (l32 == 0) csp_sh[tid >> 5] = cslr;
    __syncthreads();
    if (rep == 0) {
#pragma unroll
      for (int m = 0; m < 3; m++) {
        float4 o4 = *(const float4*)&scratch[((m << 3) + tA) * 128 + d4];
        acc.x += o4.x;
        acc.y += o4.y;
        acc.z += o4.z;
        acc.w += o4.w;
      }
      *(float4*)&ac_sh[tA][d4] = acc;
    }
    if (tid < T_CAPS)
      csum_sh[tid] = csp_sh[tid * 4] + csp_sh[tid * 4 + 1] + csp_sh[tid * 4 + 2] +
                     csp_sh[tid * 4 + 3];
    __syncthreads();
  }
}

extern "C" void kernel_launch(void* const* d_in, const int* in_sizes, int n_in, void* d_out,
                              int out_size, void* d_ws, size_t ws_size, hipStream_t stream) {
  const float* x = (const float*)d_in[0];
  const float* ew = (const float*)d_in[1];
  const float* gamma = (const float*)d_in[2];
  const float* beta = (const float*)d_in[3];
  const float* W = (const float*)d_in[4];
  const float* bias = (const float*)d_in[5];
  const int* eidx = (const int*)d_in[6];
  const int* batch = (const int*)d_in[7];
  float* out = (float*)d_out;
  float* w = (float*)d_ws;

  const int* row = eidx;
  const int* col = eidx + N_EDGES;

  int* cnt_in = (int*)w;                       // N (zeroed in prep)
  int* cursor = cnt_in + N_NODES;              // N (zeroed in prep)
  int* start = cursor + N_NODES;               // 258 (even pad)
  int* node_start = start + 258;               // N
  int* bsum = node_start + N_NODES;            // 256
  float* scale = (float*)(bsum + 256);         // 128
  float* shift = scale + 128;                  // 128
  float* dis = shift + 128;                    // N
  float* rawxsum = dis + N_NODES;              // 256*128
  float* rawxsq = rawxsum + N_GRAPHS * D_DIM;  // 256*128
  float* WT = rawxsq + N_GRAPHS * D_DIM;       // 131072
  int2* csr = (int2*)(WT + T_CAPS * D_DIM * D_DIM);          // E
  __hip_bfloat162* y = (__hip_bfloat162*)(csr + N_EDGES);    // N*64
  unsigned* agg_bf = (unsigned*)(y + (size_t)N_NODES * 64);  // N*64 (packed bf16x2)

  prep<<<N_NODES / 256, 256, 0, stream>>>(batch, W, start, cnt_in, cursor, WT);
  edge_hist<<<N_EDGES / 256, 256, 0, stream>>>(col, cnt_in);
  scan_part<<<200, 256, 0, stream>>>(cnt_in, bsum);
  scan_fin2<<<200, 256, 0, stream>>>(cnt_in, bsum, node_start);
  fill_csr<<<N_EDGES / 256, 256, 0, stream>>>(row, col, ew, node_start, cursor, csr);
  xstats<<<N_GRAPHS, 512, 0, stream>>>(x, start, rawxsum, rawxsq);
  finalize_bn<<<D_DIM, 256, 0, stream>>>(rawxsum, rawxsq, gamma, beta, scale, shift);
  make_y<<<N_NODES / 4, 256, 0, stream>>>(x, scale, shift, node_start, cnt_in, csr, dis, y);
  node_gather<<<N_NODES / 4, 256, 0, stream>>>(y, dis, node_start, cnt_in, csr,
                                               (__hip_bfloat162*)agg_bf);
  routing_fused<<<N_GRAPHS, 1024, 0, stream>>>(agg_bf, start, W, WT, bias, rawxsum, scale,
                                               shift, out);
}